// Round 3
// baseline (547.814 us; speedup 1.0000x reference)
//
#include <hip/hip_runtime.h>
#include <math.h>

#define BB 128
#define NN 256
#define EE 2048
#define BINS 16

typedef unsigned short u16;

// ---------------- CSR build, both sides: g in [0,2B) ----------------
__global__ void csr_kernel(const int* __restrict__ eq, const int* __restrict__ ec,
                           int* __restrict__ off, u16* __restrict__ srcs,
                           float* __restrict__ dvsg) {
    int g = blockIdx.x;                 // 0..2B-1
    int b = g < BB ? g : g - BB;
    const int* ei = g < BB ? eq : ec;
    int t = threadIdx.x;  // 256
    __shared__ int cnt[NN];
    __shared__ int sa[NN], sb[NN];
    __shared__ int cursor[NN];
    cnt[t] = 0;
    __syncthreads();
    const int* src = ei + b * 2 * EE;
    const int* dst = src + EE;
    for (int e = t; e < EE; e += 256) atomicAdd(&cnt[dst[e]], 1);
    __syncthreads();
    dvsg[g * NN + t] = rsqrtf((float)cnt[t] + 1.0f);   // deg^-1/2 (incl self-loop)
    sa[t] = cnt[t];
    __syncthreads();
    int* pin = sa; int* pout = sb;
    for (int d = 1; d < NN; d <<= 1) {
        int v = pin[t];
        if (t >= d) v += pin[t - d];
        pout[t] = v;
        __syncthreads();
        int* tmp = pin; pin = pout; pout = tmp;
    }
    int excl = pin[t] - cnt[t];
    off[g * 257 + t] = excl;
    if (t == 255) off[g * 257 + 256] = EE;
    cursor[t] = excl;
    __syncthreads();
    for (int e = t; e < EE; e += 256) {
        int d = dst[e], s = src[e];
        int pos = atomicAdd(&cursor[d], 1);
        srcs[g * EE + pos] = (u16)s;
    }
}

// ---------------- dense GEMM: H = X @ W  (rows = 2B*NN, cols = FOUT) ----------------
// 256 thr, per-thread 4x4, tile = TILE_R x FOUT, k-tile 16. LDS ~9-12KB -> 4 blocks/CU.
// W pointer may be a column-slice of a wider matrix (row stride WLD).
template<int FIN, int FOUT, int WLD>
__global__ __launch_bounds__(256, 4) void gemm_k(
        const float* __restrict__ X0, const float* __restrict__ X1,
        const float* __restrict__ W, float* __restrict__ H) {
    constexpr int NCG = FOUT / 4;        // col groups (16 or 8)
    constexpr int NRG = 256 / NCG;       // row groups (16 or 32)
    constexpr int TILE_R = NRG * 4;      // 64 or 128
    constexpr int XSTR = TILE_R + 4;
    constexpr int NF4 = TILE_R / 64;     // x-stage float4s per thread (1 or 2)
    __shared__ float xsT[16 * XSTR];     // k-major [k][row]
    __shared__ float wt[16 * FOUT];      // [k][c]
    int t = threadIdx.x;
    size_t row0 = (size_t)blockIdx.x * TILE_R;

    // per-thread staging pointers (rows fixed for whole kernel)
    const float* xp[NF4];
#pragma unroll
    for (int i = 0; i < NF4; i++) {
        int f = t + 256 * i;
        int r = f >> 2;                   // local row
        size_t gr = row0 + r;
        const float* base = (gr < (size_t)BB * NN)
                            ? X0 + gr * FIN
                            : X1 + (gr - (size_t)BB * NN) * FIN;
        xp[i] = base + (f & 3) * 4;
    }
    float4 xa[NF4];
#pragma unroll
    for (int i = 0; i < NF4; i++) xa[i] = *(const float4*)xp[i];

    int wrow, wcol; bool wact;
    if (FOUT == 64) { wrow = t >> 4; wcol = (t & 15) * 4; wact = true; }
    else            { wrow = t >> 3; wcol = (t & 7) * 4;  wact = (t < 128); }
    float4 wa4 = make_float4(0.f, 0.f, 0.f, 0.f);
    if (wact) wa4 = *(const float4*)&W[(size_t)wrow * WLD + wcol];

    int colg = t & (NCG - 1); int cg = colg * 4;
    int rowg = t / NCG;       int rg = rowg * 4;

    float acc[4][4];
#pragma unroll
    for (int i = 0; i < 4; i++)
#pragma unroll
        for (int j = 0; j < 4; j++) acc[i][j] = 0.f;

    for (int k0 = 0; k0 < FIN; k0 += 16) {
#pragma unroll
        for (int i = 0; i < NF4; i++) {
            int f = t + 256 * i;
            int r = f >> 2;
            int kq = (f & 3) * 4;
            xsT[(kq + 0) * XSTR + r] = xa[i].x;
            xsT[(kq + 1) * XSTR + r] = xa[i].y;
            xsT[(kq + 2) * XSTR + r] = xa[i].z;
            xsT[(kq + 3) * XSTR + r] = xa[i].w;
        }
        if (wact) *(float4*)&wt[wrow * FOUT + wcol] = wa4;
        __syncthreads();
        if (k0 + 16 < FIN) {
#pragma unroll
            for (int i = 0; i < NF4; i++) xa[i] = *(const float4*)(xp[i] + k0 + 16);
            if (wact) wa4 = *(const float4*)&W[(size_t)(k0 + 16 + wrow) * WLD + wcol];
        }
#pragma unroll
        for (int k = 0; k < 16; k++) {
            float4 xv = *(const float4*)&xsT[k * XSTR + rg];   // 8/16-lane broadcast
            float4 wv = *(const float4*)&wt[k * FOUT + cg];    // 2-way max
            acc[0][0] += xv.x * wv.x; acc[0][1] += xv.x * wv.y;
            acc[0][2] += xv.x * wv.z; acc[0][3] += xv.x * wv.w;
            acc[1][0] += xv.y * wv.x; acc[1][1] += xv.y * wv.y;
            acc[1][2] += xv.y * wv.z; acc[1][3] += xv.y * wv.w;
            acc[2][0] += xv.z * wv.x; acc[2][1] += xv.z * wv.y;
            acc[2][2] += xv.z * wv.z; acc[2][3] += xv.z * wv.w;
            acc[3][0] += xv.w * wv.x; acc[3][1] += xv.w * wv.y;
            acc[3][2] += xv.w * wv.z; acc[3][3] += xv.w * wv.w;
        }
        __syncthreads();
    }
#pragma unroll
    for (int i = 0; i < 4; i++) {
        *(float4*)&H[(row0 + rg + i) * FOUT + cg] =
            make_float4(acc[i][0], acc[i][1], acc[i][2], acc[i][3]);
    }
}

// ---------------- CSR gather: OUT[n] = sum_e w_e * H[src_e] + H[n]/deg + bias ----------------
// one block per (graph, 32-col chunk). LDS ~40KB -> 4 blocks/CU.
template<int FH, int OLD, bool RELU>
__global__ __launch_bounds__(256, 4) void gather_k(
        const float* __restrict__ H, const float* __restrict__ bias,
        const int* __restrict__ off, const u16* __restrict__ srcs,
        const float* __restrict__ dvsg, float* __restrict__ OUT) {
    constexpr int NCH = FH / 32;
    int blk = blockIdx.x;
    int g = blk / NCH, ch = blk % NCH;
    int cb = ch * 32;
    __shared__ float hT[NN * 33];
    __shared__ int   eoff[NN + 1];
    __shared__ u16   esrc[EE];
    __shared__ float dvs_s[NN];
    int t = threadIdx.x;
    const float* Hg = H + (size_t)g * NN * FH + cb;
#pragma unroll
    for (int i = 0; i < 8; i++) {
        int idx = t + 256 * i;            // float4 index over 256*32/4 = 2048
        int n = idx >> 3, c4 = (idx & 7) * 4;
        float4 v = *(const float4*)&Hg[(size_t)n * FH + c4];
        hT[n * 33 + c4 + 0] = v.x;
        hT[n * 33 + c4 + 1] = v.y;
        hT[n * 33 + c4 + 2] = v.z;
        hT[n * 33 + c4 + 3] = v.w;
    }
    const u16* sr = srcs + (size_t)g * EE;
    for (int i = t; i < EE; i += 256) esrc[i] = sr[i];
    const int* o = off + g * 257;
    for (int i = t; i <= NN; i += 256) eoff[i] = o[i];
    dvs_s[t] = dvsg[g * NN + t];
    __syncthreads();

    int c = t & 31, ng = t >> 5;
    float bb_ = bias[cb + c];
    float* outp = OUT + (size_t)g * NN * OLD + cb + c;
    for (int n = ng; n < NN; n += 8) {
        int j0 = eoff[n], j1 = eoff[n + 1];
        float dn = dvs_s[n];
        float a = 0.f;
        for (int j = j0; j < j1; j++) {
            int s = esrc[j];
            a += hT[s * 33 + c] * (dvs_s[s] * dn);
        }
        float d0i = 1.0f / ((float)(j1 - j0) + 1.0f);   // self-loop norm 1/deg
        float val = a + hT[n * 33 + c] * d0i + bb_;
        if (RELU) val = fmaxf(val, 0.f);
        outp[(size_t)n * OLD] = val;
    }
}

// ---------------- attention pooling (both sides): one block per graph ----------------
__global__ void attpool_kernel(const float* __restrict__ X, const float* __restrict__ Watt,
                               float* __restrict__ e) {
    int g = blockIdx.x;   // 0..2B-1
    int t = threadIdx.x;
    __shared__ float xs[NN * 33];
    __shared__ float red[256];
    __shared__ float mean_s[32], ctx_s[32], sc[NN];
    const float* x = X + (size_t)g * NN * 32;
    for (int i = t; i < NN * 32; i += 256) { int n = i >> 5, c = i & 31; xs[n * 33 + c] = x[i]; }
    __syncthreads();
    {
        int c = t & 31, p = t >> 5;
        float s = 0.f;
        for (int n = p * 32; n < (p + 1) * 32; n++) s += xs[n * 33 + c];
        red[t] = s;
    }
    __syncthreads();
    if (t < 32) {
        float m = 0.f;
        for (int p = 0; p < 8; p++) m += red[p * 32 + t];
        mean_s[t] = m / (float)NN;
    }
    __syncthreads();
    if (t < 32) {
        float a = 0.f;
        for (int f = 0; f < 32; f++) a += mean_s[f] * Watt[t * 32 + f];
        ctx_s[t] = tanhf(a);
    }
    __syncthreads();
    {
        float a = 0.f;
        for (int f = 0; f < 32; f++) a += xs[t * 33 + f] * ctx_s[f];
        sc[t] = 1.f / (1.f + expf(-a));
    }
    __syncthreads();
    {
        int c = t & 31, p = t >> 5;
        float s = 0.f;
        for (int n = p * 32; n < (p + 1) * 32; n++) s += xs[n * 33 + c] * sc[n];
        red[t] = s;
    }
    __syncthreads();
    if (t < 32) {
        float s = 0.f;
        for (int p = 0; p < 8; p++) s += red[p * 32 + t];
        e[g * 32 + t] = s;
    }
}

// ---------------- pairwise dots: 128x128 tile, 8x8 per thread, f-major LDS ----------------
#define PD_STAGE_AND_DOT \
    int blk = blockIdx.x; \
    int b = blk >> 2; \
    int tq = (blk >> 1) & 1, tc = blk & 1; \
    __shared__ float qsT[32 * 132]; \
    __shared__ float csT[32 * 132]; \
    int t = threadIdx.x; \
    { \
        int n = t >> 1, f0 = (t & 1) * 16; \
        const float* qp = Q + ((size_t)b * NN + tq * 128 + n) * 32 + f0; \
        const float* cp = C + ((size_t)b * NN + tc * 128 + n) * 32 + f0; \
        float qa16[16], ca16[16]; \
        *(float4*)&qa16[0]  = *(const float4*)(qp); \
        *(float4*)&qa16[4]  = *(const float4*)(qp + 4); \
        *(float4*)&qa16[8]  = *(const float4*)(qp + 8); \
        *(float4*)&qa16[12] = *(const float4*)(qp + 12); \
        *(float4*)&ca16[0]  = *(const float4*)(cp); \
        *(float4*)&ca16[4]  = *(const float4*)(cp + 4); \
        *(float4*)&ca16[8]  = *(const float4*)(cp + 8); \
        *(float4*)&ca16[12] = *(const float4*)(cp + 12); \
        _Pragma("unroll") \
        for (int m = 0; m < 16; m++) { \
            qsT[(f0 + m) * 132 + n] = qa16[m]; \
            csT[(f0 + m) * 132 + n] = ca16[m]; \
        } \
    } \
    __syncthreads(); \
    int rg = (t >> 4) * 4, cg = (t & 15) * 4; \
    float acc[8][8]; \
    _Pragma("unroll") \
    for (int i = 0; i < 8; i++) \
        _Pragma("unroll") \
        for (int j = 0; j < 8; j++) acc[i][j] = 0.f; \
    _Pragma("unroll 2") \
    for (int f = 0; f < 32; f++) { \
        float4 qa = *(const float4*)&qsT[f * 132 + rg]; \
        float4 qb = *(const float4*)&qsT[f * 132 + 64 + rg]; \
        float4 ca = *(const float4*)&csT[f * 132 + cg]; \
        float4 cb = *(const float4*)&csT[f * 132 + 64 + cg]; \
        float qv[8] = {qa.x, qa.y, qa.z, qa.w, qb.x, qb.y, qb.z, qb.w}; \
        float cv[8] = {ca.x, ca.y, ca.z, ca.w, cb.x, cb.y, cb.z, cb.w}; \
        _Pragma("unroll") \
        for (int i = 0; i < 8; i++) \
            _Pragma("unroll") \
            for (int j = 0; j < 8; j++) acc[i][j] += qv[i] * cv[j]; \
    }

__global__ __launch_bounds__(256, 4) void pairdot_minmax(
        const float* __restrict__ Q, const float* __restrict__ C,
        float* __restrict__ bmin, float* __restrict__ bmax) {
    PD_STAGE_AND_DOT
    float lmin = acc[0][0], lmax = acc[0][0];
#pragma unroll
    for (int i = 0; i < 8; i++)
#pragma unroll
        for (int j = 0; j < 8; j++) {
            lmin = fminf(lmin, acc[i][j]);
            lmax = fmaxf(lmax, acc[i][j]);
        }
    __shared__ float rmin[256], rmax[256];
    rmin[t] = lmin; rmax[t] = lmax;
    __syncthreads();
    for (int s = 128; s > 0; s >>= 1) {
        if (t < s) { rmin[t] = fminf(rmin[t], rmin[t + s]); rmax[t] = fmaxf(rmax[t], rmax[t + s]); }
        __syncthreads();
    }
    if (t == 0) { bmin[blk] = rmin[0]; bmax[blk] = rmax[0]; }
}

// ---------------- global min/max reduce (1 block) + zero counts ----------------
__global__ void minmax_kernel(const float* __restrict__ bmin, const float* __restrict__ bmax,
                              float* __restrict__ lohi, float* __restrict__ counts) {
    __shared__ float rmin[256], rmax[256];
    int t = threadIdx.x;
    float lmin = 1e30f, lmax = -1e30f;
    for (int i = t; i < 512; i += 256) { lmin = fminf(lmin, bmin[i]); lmax = fmaxf(lmax, bmax[i]); }
    rmin[t] = lmin; rmax[t] = lmax;
    __syncthreads();
    for (int s = 128; s > 0; s >>= 1) {
        if (t < s) { rmin[t] = fminf(rmin[t], rmin[t + s]); rmax[t] = fmaxf(rmax[t], rmax[t + s]); }
        __syncthreads();
    }
    if (t == 0) { lohi[0] = rmin[0]; lohi[1] = rmax[0]; }
    if (t < BINS) counts[t] = 0.f;
}

// ---------------- pass 2: recompute dots, bit-sliced ballot histogram ----------------
__global__ __launch_bounds__(256, 4) void pairdot_hist(
        const float* __restrict__ Q, const float* __restrict__ C,
        const float* __restrict__ lohi, float* __restrict__ counts) {
    PD_STAGE_AND_DOT
    float lo = lohi[0], hi = lohi[1];
    float scale = (float)BINS / (hi - lo);
    int lane = t & 63;
    int cnt = 0;   // lane L accumulates count for bin (L & 15)
#pragma unroll
    for (int i = 0; i < 8; i++)
#pragma unroll
        for (int j = 0; j < 8; j++) {
            int idx = (int)floorf((acc[i][j] - lo) * scale);
            idx = min(max(idx, 0), BINS - 1);
            unsigned long long b0 = __ballot((idx & 1) != 0);
            unsigned long long b1 = __ballot((idx & 2) != 0);
            unsigned long long b2 = __ballot((idx & 4) != 0);
            unsigned long long b3 = __ballot((idx & 8) != 0);
            unsigned long long msk = ((lane & 1) ? b0 : ~b0);
            msk &= ((lane & 2) ? b1 : ~b1);
            msk &= ((lane & 4) ? b2 : ~b2);
            msk &= ((lane & 8) ? b3 : ~b3);
            cnt += __popcll(msk);
        }
    __shared__ float wbins[4][BINS];
    int wave = t >> 6;
    if (lane < BINS) wbins[wave][lane] = (float)cnt;
    __syncthreads();
    if (t < BINS) {
        atomicAdd(&counts[t], wbins[0][t] + wbins[1][t] + wbins[2][t] + wbins[3][t]);
    }
}

// ---------------- NTN + histogram concat + fc1 + fc2 head ----------------
__global__ void final_kernel(const float* __restrict__ e1, const float* __restrict__ e2,
                             const float* __restrict__ ntnW, const float* __restrict__ ntnV,
                             const float* __restrict__ ntnb, const float* __restrict__ counts,
                             const float* __restrict__ fc1W, const float* __restrict__ fc1b,
                             const float* __restrict__ fc2W, const float* __restrict__ fc2b,
                             float* __restrict__ out) {
    int b = blockIdx.x;
    int t = threadIdx.x;
    __shared__ float a1[32], a2[32], red[256], z[32], u[16];
    if (t < 32) a1[t] = e1[b * 32 + t];
    else if (t < 64) a2[t - 32] = e2[b * 32 + t - 32];
    __syncthreads();
    int tt = t >> 4, g = t & 15;
    float p = 0.f;
#pragma unroll
    for (int ii = 0; ii < 2; ii++) {
        int i = g + 16 * ii;
        float d = 0.f;
        const float* wr = ntnW + (tt * 32 + i) * 32;
        for (int j = 0; j < 32; j++) d += wr[j] * a2[j];
        p += a1[i] * d;
    }
    red[t] = p;
    __syncthreads();
    if (t < 16) {
        float s = 0.f;
        for (int g2 = 0; g2 < 16; g2++) s += red[t * 16 + g2];
        float lin = ntnb[t];
        for (int i = 0; i < 32; i++) lin += ntnV[t * 64 + i] * a1[i];
        for (int i = 0; i < 32; i++) lin += ntnV[t * 64 + 32 + i] * a2[i];
        z[t] = fmaxf(s + lin, 0.f);
    } else if (t < 32) {
        float tot = 0.f;
        for (int i = 0; i < BINS; i++) tot += counts[i];
        z[t] = counts[t - 16] / tot;
    }
    __syncthreads();
    if (t < 16) {
        float a = fc1b[t];
        for (int i = 0; i < 32; i++) a += fc1W[t * 32 + i] * z[i];
        u[t] = fmaxf(a, 0.f);
    }
    __syncthreads();
    if (t == 0) {
        float a = fc2b[0];
        for (int i = 0; i < 16; i++) a += fc2W[i] * u[i];
        out[b] = 1.f / (1.f + expf(-a));
    }
}

extern "C" void kernel_launch(void* const* d_in, const int* in_sizes, int n_in,
                              void* d_out, int out_size, void* d_ws, size_t ws_size,
                              hipStream_t stream) {
    const float* xq   = (const float*)d_in[0];
    const float* xc   = (const float*)d_in[1];
    const int*   eq   = (const int*)d_in[2];
    const int*   ec   = (const int*)d_in[3];
    const float* W1   = (const float*)d_in[4];
    const float* b1   = (const float*)d_in[5];
    const float* W2   = (const float*)d_in[6];
    const float* b2   = (const float*)d_in[7];
    const float* W3   = (const float*)d_in[8];
    const float* b3   = (const float*)d_in[9];
    const float* Watt = (const float*)d_in[10];
    const float* ntnW = (const float*)d_in[11];
    const float* ntnV = (const float*)d_in[12];
    const float* ntnb = (const float*)d_in[13];
    const float* fc1W = (const float*)d_in[14];
    const float* fc1b = (const float*)d_in[15];
    const float* fc2W = (const float*)d_in[16];
    const float* fc2b = (const float*)d_in[17];
    float* out = (float*)d_out;
    float* ws  = (float*)d_ws;

    // ---- workspace layout (float indices), total ~60.3MB (< proven 63.4MB) ----
    float* O3   = ws;                            // 2*B*N*32  = 2097152
    float* e12  = O3 + 2097152;                  // 8192
    float* bmin = e12 + 8192;                    // 2048 (512 used)
    float* bmax = bmin + 2048;                   // 2048 (512 used)
    float* lohi = bmax + 2048;                   // 2
    float* cntw = lohi + 2;                      // 16
    int*   off  = (int*)(ws + 2109504);          // 2B*257 = 65792 ints
    u16*   srcs = (u16*)(off + 65792);           // 2B*E u16 = 262144 floats
    float* dvsg = ws + 2437440;                  // 2B*256 = 65536
    float* Htmp = ws + 2502976;                  // 65536*64 = 4194304
    float* O1   = ws + 6697280;                  // 65536*128 = 8388608
    float* O2   = O1;                            // reuse (O1 dead after gemm L2)

    float* O3Q = O3;
    float* O3C = O3 + (size_t)BB * NN * 32;
    float* e1w = e12;
    float* e2w = e12 + BB * 32;

    csr_kernel<<<2 * BB, 256, 0, stream>>>(eq, ec, off, srcs, dvsg);

    // ---- layer 1 (FIN=128, FOUT=128) in two 64-col halves through Htmp ----
    gemm_k<128, 64, 128><<<1024, 256, 0, stream>>>(xq, xc, W1, Htmp);
    gather_k<64, 128, true><<<512, 256, 0, stream>>>(Htmp, b1, off, srcs, dvsg, O1);
    gemm_k<128, 64, 128><<<1024, 256, 0, stream>>>(xq, xc, W1 + 64, Htmp);
    gather_k<64, 128, true><<<512, 256, 0, stream>>>(Htmp, b1 + 64, off, srcs, dvsg, O1 + 64);

    // ---- layer 2 (128 -> 64) ----
    gemm_k<128, 64, 64><<<1024, 256, 0, stream>>>(O1, O1 + (size_t)BB * NN * 128, W2, Htmp);
    gather_k<64, 64, true><<<512, 256, 0, stream>>>(Htmp, b2, off, srcs, dvsg, O2);

    // ---- layer 3 (64 -> 32) ----
    gemm_k<64, 32, 32><<<512, 256, 0, stream>>>(O2, O2 + (size_t)BB * NN * 64, W3, Htmp);
    gather_k<32, 32, false><<<256, 256, 0, stream>>>(Htmp, b3, off, srcs, dvsg, O3);

    attpool_kernel<<<2 * BB, 256, 0, stream>>>(O3, Watt, e12);

    pairdot_minmax<<<BB * 4, 256, 0, stream>>>(O3Q, O3C, bmin, bmax);
    minmax_kernel<<<1, 256, 0, stream>>>(bmin, bmax, lohi, cntw);
    pairdot_hist<<<BB * 4, 256, 0, stream>>>(O3Q, O3C, lohi, cntw);

    final_kernel<<<BB, 256, 0, stream>>>(e1w, e2w, ntnW, ntnV, ntnb, cntw,
                                         fc1W, fc1b, fc2W, fc2b, out);
}

// Round 4
// 367.420 us; speedup vs baseline: 1.4910x; 1.4910x over previous
//
#include <hip/hip_runtime.h>
#include <math.h>

#define BB 128
#define NN 256
#define EE 2048
#define BINS 16

typedef unsigned short u16;

// ---------------- CSR build, both sides: g in [0,2B) ----------------
__global__ void csr_kernel(const int* __restrict__ eq, const int* __restrict__ ec,
                           int* __restrict__ off, u16* __restrict__ srcs,
                           float* __restrict__ dvsg) {
    int g = blockIdx.x;                 // 0..2B-1
    int b = g < BB ? g : g - BB;
    const int* ei = g < BB ? eq : ec;
    int t = threadIdx.x;  // 256
    __shared__ int cnt[NN];
    __shared__ int sa[NN], sb[NN];
    __shared__ int cursor[NN];
    cnt[t] = 0;
    __syncthreads();
    const int* src = ei + b * 2 * EE;
    const int* dst = src + EE;
    for (int e = t; e < EE; e += 256) atomicAdd(&cnt[dst[e]], 1);
    __syncthreads();
    dvsg[g * NN + t] = rsqrtf((float)cnt[t] + 1.0f);   // deg^-1/2 (incl self-loop)
    sa[t] = cnt[t];
    __syncthreads();
    int* pin = sa; int* pout = sb;
    for (int d = 1; d < NN; d <<= 1) {
        int v = pin[t];
        if (t >= d) v += pin[t - d];
        pout[t] = v;
        __syncthreads();
        int* tmp = pin; pin = pout; pout = tmp;
    }
    int excl = pin[t] - cnt[t];
    off[g * 257 + t] = excl;
    if (t == 255) off[g * 257 + 256] = EE;
    cursor[t] = excl;
    __syncthreads();
    for (int e = t; e < EE; e += 256) {
        int d = dst[e], s = src[e];
        int pos = atomicAdd(&cursor[d], 1);
        srcs[g * EE + pos] = (u16)s;
    }
}

// ---------------- fused GCN layer (round-0 structure, union LDS) ----------------
// 512 thr, per-thread 4 rows x 4 cols, k-tile 16. LDS ~39.9KB -> 4 blocks/CU (32 waves).
// uni[] holds {xsT[16*260] + wt[16*32]} during the k-loop, then hT[256*33] after
// (xsT's last read and hT's first write are separated by the loop-tail barrier).
template<int FIN, int FOUT, bool RELU, int NSPLIT>
__global__ __launch_bounds__(512, 8) void gcn_fused4(
        const float* __restrict__ X0, const float* __restrict__ X1,
        const float* __restrict__ W, const float* __restrict__ bias,
        const int* __restrict__ off, const u16* __restrict__ srcs,
        const float* __restrict__ dvsg, float* __restrict__ OUT) {
    constexpr int CHUNKS = FOUT / 32;
    int blk = blockIdx.x;
    int g = blk % (2 * BB);
    int rest = blk / (2 * BB);
    int cb = (rest % CHUNKS) * 32;
    int half = rest / CHUNKS;          // 0..NSPLIT-1
    int t = threadIdx.x;

    __shared__ float uni[NN * 33];     // 33.8 KB union region
    __shared__ int   eoff[NN + 1];     // 1.0 KB
    __shared__ u16   esrc[EE];         // 4.0 KB
    __shared__ float dvs_s[NN];        // 1.0 KB
    float* xsT = uni;                  // [16][260] k-major, 4160 floats
    float* wt  = uni + 16 * 260;       // [16][32], 512 floats (ends at 4672 < 8448)
    float* hT  = uni;                  // [256][33] after the k-loop

    const float* xg = (g < BB) ? (X0 + (size_t)g * NN * FIN)
                               : (X1 + (size_t)(g - BB) * NN * FIN);
    const int* o = off + g * 257;
    const u16* sr = srcs + (size_t)g * EE;

    // stage edges + offsets + dvs (coalesced; overlaps k-loop prologue)
    for (int i = t; i < EE; i += 512) esrc[i] = sr[i];
    for (int i = t; i <= NN; i += 512) eoff[i] = o[i];
    if (t < NN) dvs_s[t] = dvsg[g * NN + t];

    int l = t & 63;        // lane -> node quad (rows 4l..4l+3)
    int wv = t >> 6;       // wave -> channel quad (cols 4wv..4wv+3)

    float acc[4][4];
#pragma unroll
    for (int i = 0; i < 4; i++)
#pragma unroll
        for (int j = 0; j < 4; j++) acc[i][j] = 0.f;

    int sn = t >> 1, qk = (t & 1) * 8;
    const float* xr = xg + sn * FIN + qk;
    float4 v0 = *(const float4*)xr;
    float4 v1 = *(const float4*)(xr + 4);
    float wreg = W[(t >> 5) * FOUT + cb + (t & 31)];

    for (int k0 = 0; k0 < FIN; k0 += 16) {
        xsT[(qk + 0) * 260 + sn] = v0.x;
        xsT[(qk + 1) * 260 + sn] = v0.y;
        xsT[(qk + 2) * 260 + sn] = v0.z;
        xsT[(qk + 3) * 260 + sn] = v0.w;
        xsT[(qk + 4) * 260 + sn] = v1.x;
        xsT[(qk + 5) * 260 + sn] = v1.y;
        xsT[(qk + 6) * 260 + sn] = v1.z;
        xsT[(qk + 7) * 260 + sn] = v1.w;
        wt[t] = wreg;
        __syncthreads();
        if (k0 + 16 < FIN) {
            xr += 16;
            v0 = *(const float4*)xr;
            v1 = *(const float4*)(xr + 4);
            wreg = W[(k0 + 16 + (t >> 5)) * FOUT + cb + (t & 31)];
        }
#pragma unroll
        for (int k = 0; k < 16; k++) {
            float4 xv = *(const float4*)&xsT[k * 260 + 4 * l];
            float4 wvv = *(const float4*)&wt[k * 32 + 4 * wv];
            acc[0][0] += xv.x * wvv.x; acc[0][1] += xv.x * wvv.y;
            acc[0][2] += xv.x * wvv.z; acc[0][3] += xv.x * wvv.w;
            acc[1][0] += xv.y * wvv.x; acc[1][1] += xv.y * wvv.y;
            acc[1][2] += xv.y * wvv.z; acc[1][3] += xv.y * wvv.w;
            acc[2][0] += xv.z * wvv.x; acc[2][1] += xv.z * wvv.y;
            acc[2][2] += xv.z * wvv.z; acc[2][3] += xv.z * wvv.w;
            acc[3][0] += xv.w * wvv.x; acc[3][1] += xv.w * wvv.y;
            acc[3][2] += xv.w * wvv.z; acc[3][3] += xv.w * wvv.w;
        }
        __syncthreads();   // last iteration: all xsT reads done -> hT may overwrite
    }
#pragma unroll
    for (int i = 0; i < 4; i++)
#pragma unroll
        for (int j = 0; j < 4; j++)
            hT[(4 * l + i) * 33 + 4 * wv + j] = acc[i][j];
    __syncthreads();

    // CSR-gather aggregation: everything in LDS; edge weight = dvs[s]*dvs[n]
    int c = t & 31, ng = t >> 5;
    float bb_ = bias[cb + c];
    float* outp = OUT + (size_t)g * NN * FOUT;
    constexpr int NSEG = NN / NSPLIT;
    int nlo = half * NSEG, nhi = nlo + NSEG;
    for (int n = nlo + ng; n < nhi; n += 16) {
        int j0 = eoff[n], j1 = eoff[n + 1];
        float dn = dvs_s[n];
        float a = 0.f;
        int j = j0;
        for (; j + 1 < j1; j += 2) {
            int s0 = esrc[j], s1 = esrc[j + 1];
            a += hT[s0 * 33 + c] * (dvs_s[s0] * dn);
            a += hT[s1 * 33 + c] * (dvs_s[s1] * dn);
        }
        if (j < j1) {
            int s0 = esrc[j];
            a += hT[s0 * 33 + c] * (dvs_s[s0] * dn);
        }
        float d0i = 1.0f / ((float)(j1 - j0) + 1.0f);   // self-loop norm 1/deg
        float val = a + hT[n * 33 + c] * d0i + bb_;
        if (RELU) val = fmaxf(val, 0.f);
        outp[n * FOUT + cb + c] = val;
    }
}

// ---------------- attention pooling (both sides): one block per graph ----------------
__global__ void attpool_kernel(const float* __restrict__ X, const float* __restrict__ Watt,
                               float* __restrict__ e) {
    int g = blockIdx.x;   // 0..2B-1
    int t = threadIdx.x;
    __shared__ float xs[NN * 33];
    __shared__ float red[256];
    __shared__ float mean_s[32], ctx_s[32], sc[NN];
    const float* x = X + (size_t)g * NN * 32;
    for (int i = t; i < NN * 32; i += 256) { int n = i >> 5, c = i & 31; xs[n * 33 + c] = x[i]; }
    __syncthreads();
    {
        int c = t & 31, p = t >> 5;
        float s = 0.f;
        for (int n = p * 32; n < (p + 1) * 32; n++) s += xs[n * 33 + c];
        red[t] = s;
    }
    __syncthreads();
    if (t < 32) {
        float m = 0.f;
        for (int p = 0; p < 8; p++) m += red[p * 32 + t];
        mean_s[t] = m / (float)NN;
    }
    __syncthreads();
    if (t < 32) {
        float a = 0.f;
        for (int f = 0; f < 32; f++) a += mean_s[f] * Watt[t * 32 + f];
        ctx_s[t] = tanhf(a);
    }
    __syncthreads();
    {
        float a = 0.f;
        for (int f = 0; f < 32; f++) a += xs[t * 33 + f] * ctx_s[f];
        sc[t] = 1.f / (1.f + expf(-a));
    }
    __syncthreads();
    {
        int c = t & 31, p = t >> 5;
        float s = 0.f;
        for (int n = p * 32; n < (p + 1) * 32; n++) s += xs[n * 33 + c] * sc[n];
        red[t] = s;
    }
    __syncthreads();
    if (t < 32) {
        float s = 0.f;
        for (int p = 0; p < 8; p++) s += red[p * 32 + t];
        e[g * 32 + t] = s;
    }
}

// ---------------- pairwise dots: 128x128 tile, 8x8 per thread, f-major LDS ----------------
#define PD_STAGE_AND_DOT \
    int blk = blockIdx.x; \
    int b = blk >> 2; \
    int tq = (blk >> 1) & 1, tc = blk & 1; \
    __shared__ float qsT[32 * 132]; \
    __shared__ float csT[32 * 132]; \
    int t = threadIdx.x; \
    { \
        int n = t >> 1, f0 = (t & 1) * 16; \
        const float* qp = Q + ((size_t)b * NN + tq * 128 + n) * 32 + f0; \
        const float* cp = C + ((size_t)b * NN + tc * 128 + n) * 32 + f0; \
        float qa16[16], ca16[16]; \
        *(float4*)&qa16[0]  = *(const float4*)(qp); \
        *(float4*)&qa16[4]  = *(const float4*)(qp + 4); \
        *(float4*)&qa16[8]  = *(const float4*)(qp + 8); \
        *(float4*)&qa16[12] = *(const float4*)(qp + 12); \
        *(float4*)&ca16[0]  = *(const float4*)(cp); \
        *(float4*)&ca16[4]  = *(const float4*)(cp + 4); \
        *(float4*)&ca16[8]  = *(const float4*)(cp + 8); \
        *(float4*)&ca16[12] = *(const float4*)(cp + 12); \
        _Pragma("unroll") \
        for (int m = 0; m < 16; m++) { \
            qsT[(f0 + m) * 132 + n] = qa16[m]; \
            csT[(f0 + m) * 132 + n] = ca16[m]; \
        } \
    } \
    __syncthreads(); \
    int rg = (t >> 4) * 4, cg = (t & 15) * 4; \
    float acc[8][8]; \
    _Pragma("unroll") \
    for (int i = 0; i < 8; i++) \
        _Pragma("unroll") \
        for (int j = 0; j < 8; j++) acc[i][j] = 0.f; \
    _Pragma("unroll 2") \
    for (int f = 0; f < 32; f++) { \
        float4 qa = *(const float4*)&qsT[f * 132 + rg]; \
        float4 qb = *(const float4*)&qsT[f * 132 + 64 + rg]; \
        float4 ca = *(const float4*)&csT[f * 132 + cg]; \
        float4 cb = *(const float4*)&csT[f * 132 + 64 + cg]; \
        float qv[8] = {qa.x, qa.y, qa.z, qa.w, qb.x, qb.y, qb.z, qb.w}; \
        float cv[8] = {ca.x, ca.y, ca.z, ca.w, cb.x, cb.y, cb.z, cb.w}; \
        _Pragma("unroll") \
        for (int i = 0; i < 8; i++) \
            _Pragma("unroll") \
            for (int j = 0; j < 8; j++) acc[i][j] += qv[i] * cv[j]; \
    }

__global__ __launch_bounds__(256, 4) void pairdot_minmax(
        const float* __restrict__ Q, const float* __restrict__ C,
        float* __restrict__ bmin, float* __restrict__ bmax) {
    PD_STAGE_AND_DOT
    float lmin = acc[0][0], lmax = acc[0][0];
#pragma unroll
    for (int i = 0; i < 8; i++)
#pragma unroll
        for (int j = 0; j < 8; j++) {
            lmin = fminf(lmin, acc[i][j]);
            lmax = fmaxf(lmax, acc[i][j]);
        }
    __shared__ float rmin[256], rmax[256];
    rmin[t] = lmin; rmax[t] = lmax;
    __syncthreads();
    for (int s = 128; s > 0; s >>= 1) {
        if (t < s) { rmin[t] = fminf(rmin[t], rmin[t + s]); rmax[t] = fmaxf(rmax[t], rmax[t + s]); }
        __syncthreads();
    }
    if (t == 0) { bmin[blk] = rmin[0]; bmax[blk] = rmax[0]; }
}

// ---------------- global min/max reduce (1 block) + zero counts ----------------
__global__ void minmax_kernel(const float* __restrict__ bmin, const float* __restrict__ bmax,
                              float* __restrict__ lohi, float* __restrict__ counts) {
    __shared__ float rmin[256], rmax[256];
    int t = threadIdx.x;
    float lmin = 1e30f, lmax = -1e30f;
    for (int i = t; i < 512; i += 256) { lmin = fminf(lmin, bmin[i]); lmax = fmaxf(lmax, bmax[i]); }
    rmin[t] = lmin; rmax[t] = lmax;
    __syncthreads();
    for (int s = 128; s > 0; s >>= 1) {
        if (t < s) { rmin[t] = fminf(rmin[t], rmin[t + s]); rmax[t] = fmaxf(rmax[t], rmax[t + s]); }
        __syncthreads();
    }
    if (t == 0) { lohi[0] = rmin[0]; lohi[1] = rmax[0]; }
    if (t < BINS) counts[t] = 0.f;
}

// ---------------- pass 2: recompute dots, bit-sliced ballot histogram ----------------
__global__ __launch_bounds__(256, 4) void pairdot_hist(
        const float* __restrict__ Q, const float* __restrict__ C,
        const float* __restrict__ lohi, float* __restrict__ counts) {
    PD_STAGE_AND_DOT
    float lo = lohi[0], hi = lohi[1];
    float scale = (float)BINS / (hi - lo);
    int lane = t & 63;
    int cnt = 0;   // lane L accumulates count for bin (L & 15)
#pragma unroll
    for (int i = 0; i < 8; i++)
#pragma unroll
        for (int j = 0; j < 8; j++) {
            int idx = (int)floorf((acc[i][j] - lo) * scale);
            idx = min(max(idx, 0), BINS - 1);
            unsigned long long b0 = __ballot((idx & 1) != 0);
            unsigned long long b1 = __ballot((idx & 2) != 0);
            unsigned long long b2 = __ballot((idx & 4) != 0);
            unsigned long long b3 = __ballot((idx & 8) != 0);
            unsigned long long msk = ((lane & 1) ? b0 : ~b0);
            msk &= ((lane & 2) ? b1 : ~b1);
            msk &= ((lane & 4) ? b2 : ~b2);
            msk &= ((lane & 8) ? b3 : ~b3);
            cnt += __popcll(msk);
        }
    __shared__ float wbins[4][BINS];
    int wave = t >> 6;
    if (lane < BINS) wbins[wave][lane] = (float)cnt;
    __syncthreads();
    if (t < BINS) {
        atomicAdd(&counts[t], wbins[0][t] + wbins[1][t] + wbins[2][t] + wbins[3][t]);
    }
}

// ---------------- NTN + histogram concat + fc1 + fc2 head ----------------
__global__ void final_kernel(const float* __restrict__ e1, const float* __restrict__ e2,
                             const float* __restrict__ ntnW, const float* __restrict__ ntnV,
                             const float* __restrict__ ntnb, const float* __restrict__ counts,
                             const float* __restrict__ fc1W, const float* __restrict__ fc1b,
                             const float* __restrict__ fc2W, const float* __restrict__ fc2b,
                             float* __restrict__ out) {
    int b = blockIdx.x;
    int t = threadIdx.x;
    __shared__ float a1[32], a2[32], red[256], z[32], u[16];
    if (t < 32) a1[t] = e1[b * 32 + t];
    else if (t < 64) a2[t - 32] = e2[b * 32 + t - 32];
    __syncthreads();
    int tt = t >> 4, g = t & 15;
    float p = 0.f;
#pragma unroll
    for (int ii = 0; ii < 2; ii++) {
        int i = g + 16 * ii;
        float d = 0.f;
        const float* wr = ntnW + (tt * 32 + i) * 32;
        for (int j = 0; j < 32; j++) d += wr[j] * a2[j];
        p += a1[i] * d;
    }
    red[t] = p;
    __syncthreads();
    if (t < 16) {
        float s = 0.f;
        for (int g2 = 0; g2 < 16; g2++) s += red[t * 16 + g2];
        float lin = ntnb[t];
        for (int i = 0; i < 32; i++) lin += ntnV[t * 64 + i] * a1[i];
        for (int i = 0; i < 32; i++) lin += ntnV[t * 64 + 32 + i] * a2[i];
        z[t] = fmaxf(s + lin, 0.f);
    } else if (t < 32) {
        float tot = 0.f;
        for (int i = 0; i < BINS; i++) tot += counts[i];
        z[t] = counts[t - 16] / tot;
    }
    __syncthreads();
    if (t < 16) {
        float a = fc1b[t];
        for (int i = 0; i < 32; i++) a += fc1W[t * 32 + i] * z[i];
        u[t] = fmaxf(a, 0.f);
    }
    __syncthreads();
    if (t == 0) {
        float a = fc2b[0];
        for (int i = 0; i < 16; i++) a += fc2W[i] * u[i];
        out[b] = 1.f / (1.f + expf(-a));
    }
}

extern "C" void kernel_launch(void* const* d_in, const int* in_sizes, int n_in,
                              void* d_out, int out_size, void* d_ws, size_t ws_size,
                              hipStream_t stream) {
    const float* xq   = (const float*)d_in[0];
    const float* xc   = (const float*)d_in[1];
    const int*   eq   = (const int*)d_in[2];
    const int*   ec   = (const int*)d_in[3];
    const float* W1   = (const float*)d_in[4];
    const float* b1   = (const float*)d_in[5];
    const float* W2   = (const float*)d_in[6];
    const float* b2   = (const float*)d_in[7];
    const float* W3   = (const float*)d_in[8];
    const float* b3   = (const float*)d_in[9];
    const float* Watt = (const float*)d_in[10];
    const float* ntnW = (const float*)d_in[11];
    const float* ntnV = (const float*)d_in[12];
    const float* ntnb = (const float*)d_in[13];
    const float* fc1W = (const float*)d_in[14];
    const float* fc1b = (const float*)d_in[15];
    const float* fc2W = (const float*)d_in[16];
    const float* fc2b = (const float*)d_in[17];
    float* out = (float*)d_out;
    float* ws  = (float*)d_ws;

    // ---- workspace layout (float indices), [2B] contiguous buffers ----
    float* O3   = ws;                            // 2*B*N*32  = 2097152
    float* e12  = O3 + 2097152;                  // 8192
    float* bmin = e12 + 8192;                    // 2048 (512 used)
    float* bmax = bmin + 2048;                   // 2048 (512 used)
    float* lohi = bmax + 2048;                   // 2
    float* cntw = lohi + 2;                      // 16
    int*   off  = (int*)(ws + 2109504);          // 2B*257 = 65792 ints
    u16*   srcs = (u16*)(off + 65792);           // 2B*E u16 = 262144 floats
    float* dvsg = ws + 2437440;                  // 2B*256 = 65536
    float* O1   = ws + 3223872;                  // 2*B*N*128 = 8388608
    float* O2   = O1 + 8388608;                  // 2*B*N*64  = 4194304

    float* O3Q = O3;
    float* O3C = O3 + (size_t)BB * NN * 32;
    float* e1w = e12;
    float* e2w = e12 + BB * 32;

    csr_kernel<<<2 * BB, 256, 0, stream>>>(eq, ec, off, srcs, dvsg);

    gcn_fused4<128, 128, true, 1><<<4 * 2 * BB, 512, 0, stream>>>(
        xq, xc, W1, b1, off, srcs, dvsg, O1);
    gcn_fused4<128, 64, true, 1><<<2 * 2 * BB, 512, 0, stream>>>(
        O1, O1 + (size_t)BB * NN * 128, W2, b2, off, srcs, dvsg, O2);
    gcn_fused4<64, 32, false, 2><<<2 * 2 * BB, 512, 0, stream>>>(
        O2, O2 + (size_t)BB * NN * 64, W3, b3, off, srcs, dvsg, O3);

    attpool_kernel<<<2 * BB, 256, 0, stream>>>(O3, Watt, e12);

    pairdot_minmax<<<BB * 4, 256, 0, stream>>>(O3Q, O3C, bmin, bmax);
    minmax_kernel<<<1, 256, 0, stream>>>(bmin, bmax, lohi, cntw);
    pairdot_hist<<<BB * 4, 256, 0, stream>>>(O3Q, O3C, lohi, cntw);

    final_kernel<<<BB, 256, 0, stream>>>(e1w, e2w, ntnW, ntnV, ntnb, cntw,
                                         fc1W, fc1b, fc2W, fc2b, out);
}

// Round 5
// 299.523 us; speedup vs baseline: 1.8290x; 1.2267x over previous
//
#include <hip/hip_runtime.h>
#include <math.h>

#define BB 128
#define NN 256
#define EE 2048
#define BINS 16

typedef unsigned short u16;

// ---------------- CSR build, both sides: g in [0,2B) ----------------
__global__ void csr_kernel(const int* __restrict__ eq, const int* __restrict__ ec,
                           int* __restrict__ off, u16* __restrict__ srcs,
                           float* __restrict__ dvsg) {
    int g = blockIdx.x;                 // 0..2B-1
    int b = g < BB ? g : g - BB;
    const int* ei = g < BB ? eq : ec;
    int t = threadIdx.x;  // 256
    __shared__ int cnt[NN];
    __shared__ int sa[NN], sb[NN];
    __shared__ int cursor[NN];
    cnt[t] = 0;
    __syncthreads();
    const int* src = ei + b * 2 * EE;
    const int* dst = src + EE;
    for (int e = t; e < EE; e += 256) atomicAdd(&cnt[dst[e]], 1);
    __syncthreads();
    dvsg[g * NN + t] = rsqrtf((float)cnt[t] + 1.0f);   // deg^-1/2 (incl self-loop)
    sa[t] = cnt[t];
    __syncthreads();
    int* pin = sa; int* pout = sb;
    for (int d = 1; d < NN; d <<= 1) {
        int v = pin[t];
        if (t >= d) v += pin[t - d];
        pout[t] = v;
        __syncthreads();
        int* tmp = pin; pin = pout; pout = tmp;
    }
    int excl = pin[t] - cnt[t];
    off[g * 257 + t] = excl;
    if (t == 255) off[g * 257 + 256] = EE;
    cursor[t] = excl;
    __syncthreads();
    for (int e = t; e < EE; e += 256) {
        int d = dst[e], s = src[e];
        int pos = atomicAdd(&cursor[d], 1);
        srcs[g * EE + pos] = (u16)s;
    }
}

// ---------------- fused GCN layer (round-0 structure, union LDS) ----------------
// 512 thr, per-thread 4 rows x 4 cols, k-tile 16. LDS ~39.9KB -> 4 blocks/CU (32 waves).
// uni[] holds {xsT[16*260] + wt[16*32]} during the k-loop, then hT[256*33] after
// (xsT's last read and hT's first write are separated by the loop-tail barrier).
// NOTE: plain __launch_bounds__(512) — round 4's (512,8) forced VGPR=32 and
// caused ~260MB/dispatch of scratch-spill traffic (FETCH 133MB/WRITE 219MB).
template<int FIN, int FOUT, bool RELU, int NSPLIT>
__global__ __launch_bounds__(512) void gcn_fused4(
        const float* __restrict__ X0, const float* __restrict__ X1,
        const float* __restrict__ W, const float* __restrict__ bias,
        const int* __restrict__ off, const u16* __restrict__ srcs,
        const float* __restrict__ dvsg, float* __restrict__ OUT) {
    constexpr int CHUNKS = FOUT / 32;
    int blk = blockIdx.x;
    int g = blk % (2 * BB);
    int rest = blk / (2 * BB);
    int cb = (rest % CHUNKS) * 32;
    int half = rest / CHUNKS;          // 0..NSPLIT-1
    int t = threadIdx.x;

    __shared__ float uni[NN * 33];     // 33.8 KB union region
    __shared__ int   eoff[NN + 1];     // 1.0 KB
    __shared__ u16   esrc[EE];         // 4.0 KB
    __shared__ float dvs_s[NN];        // 1.0 KB
    float* xsT = uni;                  // [16][260] k-major, 4160 floats
    float* wt  = uni + 16 * 260;       // [16][32], 512 floats (ends at 4672 < 8448)
    float* hT  = uni;                  // [256][33] after the k-loop

    const float* xg = (g < BB) ? (X0 + (size_t)g * NN * FIN)
                               : (X1 + (size_t)(g - BB) * NN * FIN);
    const int* o = off + g * 257;
    const u16* sr = srcs + (size_t)g * EE;

    // stage edges + offsets + dvs (coalesced; overlaps k-loop prologue)
    for (int i = t; i < EE; i += 512) esrc[i] = sr[i];
    for (int i = t; i <= NN; i += 512) eoff[i] = o[i];
    if (t < NN) dvs_s[t] = dvsg[g * NN + t];

    int l = t & 63;        // lane -> node quad (rows 4l..4l+3)
    int wv = t >> 6;       // wave -> channel quad (cols 4wv..4wv+3)

    float acc[4][4];
#pragma unroll
    for (int i = 0; i < 4; i++)
#pragma unroll
        for (int j = 0; j < 4; j++) acc[i][j] = 0.f;

    int sn = t >> 1, qk = (t & 1) * 8;
    const float* xr = xg + sn * FIN + qk;
    float4 v0 = *(const float4*)xr;
    float4 v1 = *(const float4*)(xr + 4);
    float wreg = W[(t >> 5) * FOUT + cb + (t & 31)];

    for (int k0 = 0; k0 < FIN; k0 += 16) {
        xsT[(qk + 0) * 260 + sn] = v0.x;
        xsT[(qk + 1) * 260 + sn] = v0.y;
        xsT[(qk + 2) * 260 + sn] = v0.z;
        xsT[(qk + 3) * 260 + sn] = v0.w;
        xsT[(qk + 4) * 260 + sn] = v1.x;
        xsT[(qk + 5) * 260 + sn] = v1.y;
        xsT[(qk + 6) * 260 + sn] = v1.z;
        xsT[(qk + 7) * 260 + sn] = v1.w;
        wt[t] = wreg;
        __syncthreads();
        if (k0 + 16 < FIN) {
            xr += 16;
            v0 = *(const float4*)xr;
            v1 = *(const float4*)(xr + 4);
            wreg = W[(k0 + 16 + (t >> 5)) * FOUT + cb + (t & 31)];
        }
#pragma unroll
        for (int k = 0; k < 16; k++) {
            float4 xv = *(const float4*)&xsT[k * 260 + 4 * l];
            float4 wvv = *(const float4*)&wt[k * 32 + 4 * wv];
            acc[0][0] += xv.x * wvv.x; acc[0][1] += xv.x * wvv.y;
            acc[0][2] += xv.x * wvv.z; acc[0][3] += xv.x * wvv.w;
            acc[1][0] += xv.y * wvv.x; acc[1][1] += xv.y * wvv.y;
            acc[1][2] += xv.y * wvv.z; acc[1][3] += xv.y * wvv.w;
            acc[2][0] += xv.z * wvv.x; acc[2][1] += xv.z * wvv.y;
            acc[2][2] += xv.z * wvv.z; acc[2][3] += xv.z * wvv.w;
            acc[3][0] += xv.w * wvv.x; acc[3][1] += xv.w * wvv.y;
            acc[3][2] += xv.w * wvv.z; acc[3][3] += xv.w * wvv.w;
        }
        __syncthreads();   // last iteration: all xsT reads done -> hT may overwrite
    }
#pragma unroll
    for (int i = 0; i < 4; i++)
#pragma unroll
        for (int j = 0; j < 4; j++)
            hT[(4 * l + i) * 33 + 4 * wv + j] = acc[i][j];
    __syncthreads();

    // CSR-gather aggregation: everything in LDS; edge weight = dvs[s]*dvs[n]
    int c = t & 31, ng = t >> 5;
    float bb_ = bias[cb + c];
    float* outp = OUT + (size_t)g * NN * FOUT;
    constexpr int NSEG = NN / NSPLIT;
    int nlo = half * NSEG, nhi = nlo + NSEG;
    for (int n = nlo + ng; n < nhi; n += 16) {
        int j0 = eoff[n], j1 = eoff[n + 1];
        float dn = dvs_s[n];
        float a = 0.f;
        int j = j0;
        for (; j + 1 < j1; j += 2) {
            int s0 = esrc[j], s1 = esrc[j + 1];
            a += hT[s0 * 33 + c] * (dvs_s[s0] * dn);
            a += hT[s1 * 33 + c] * (dvs_s[s1] * dn);
        }
        if (j < j1) {
            int s0 = esrc[j];
            a += hT[s0 * 33 + c] * (dvs_s[s0] * dn);
        }
        float d0i = 1.0f / ((float)(j1 - j0) + 1.0f);   // self-loop norm 1/deg
        float val = a + hT[n * 33 + c] * d0i + bb_;
        if (RELU) val = fmaxf(val, 0.f);
        outp[n * FOUT + cb + c] = val;
    }
}

// ---------------- attention pooling (both sides): one block per graph ----------------
__global__ void attpool_kernel(const float* __restrict__ X, const float* __restrict__ Watt,
                               float* __restrict__ e) {
    int g = blockIdx.x;   // 0..2B-1
    int t = threadIdx.x;
    __shared__ float xs[NN * 33];
    __shared__ float red[256];
    __shared__ float mean_s[32], ctx_s[32], sc[NN];
    const float* x = X + (size_t)g * NN * 32;
    for (int i = t; i < NN * 32; i += 256) { int n = i >> 5, c = i & 31; xs[n * 33 + c] = x[i]; }
    __syncthreads();
    {
        int c = t & 31, p = t >> 5;
        float s = 0.f;
        for (int n = p * 32; n < (p + 1) * 32; n++) s += xs[n * 33 + c];
        red[t] = s;
    }
    __syncthreads();
    if (t < 32) {
        float m = 0.f;
        for (int p = 0; p < 8; p++) m += red[p * 32 + t];
        mean_s[t] = m / (float)NN;
    }
    __syncthreads();
    if (t < 32) {
        float a = 0.f;
        for (int f = 0; f < 32; f++) a += mean_s[f] * Watt[t * 32 + f];
        ctx_s[t] = tanhf(a);
    }
    __syncthreads();
    {
        float a = 0.f;
        for (int f = 0; f < 32; f++) a += xs[t * 33 + f] * ctx_s[f];
        sc[t] = 1.f / (1.f + expf(-a));
    }
    __syncthreads();
    {
        int c = t & 31, p = t >> 5;
        float s = 0.f;
        for (int n = p * 32; n < (p + 1) * 32; n++) s += xs[n * 33 + c] * sc[n];
        red[t] = s;
    }
    __syncthreads();
    if (t < 32) {
        float s = 0.f;
        for (int p = 0; p < 8; p++) s += red[p * 32 + t];
        e[g * 32 + t] = s;
    }
}

// ---------------- pairwise dots: 128x128 tile, 8x8 per thread, f-major LDS ----------------
#define PD_STAGE_AND_DOT \
    int blk = blockIdx.x; \
    int b = blk >> 2; \
    int tq = (blk >> 1) & 1, tc = blk & 1; \
    __shared__ float qsT[32 * 132]; \
    __shared__ float csT[32 * 132]; \
    int t = threadIdx.x; \
    { \
        int n = t >> 1, f0 = (t & 1) * 16; \
        const float* qp = Q + ((size_t)b * NN + tq * 128 + n) * 32 + f0; \
        const float* cp = C + ((size_t)b * NN + tc * 128 + n) * 32 + f0; \
        float qa16[16], ca16[16]; \
        *(float4*)&qa16[0]  = *(const float4*)(qp); \
        *(float4*)&qa16[4]  = *(const float4*)(qp + 4); \
        *(float4*)&qa16[8]  = *(const float4*)(qp + 8); \
        *(float4*)&qa16[12] = *(const float4*)(qp + 12); \
        *(float4*)&ca16[0]  = *(const float4*)(cp); \
        *(float4*)&ca16[4]  = *(const float4*)(cp + 4); \
        *(float4*)&ca16[8]  = *(const float4*)(cp + 8); \
        *(float4*)&ca16[12] = *(const float4*)(cp + 12); \
        _Pragma("unroll") \
        for (int m = 0; m < 16; m++) { \
            qsT[(f0 + m) * 132 + n] = qa16[m]; \
            csT[(f0 + m) * 132 + n] = ca16[m]; \
        } \
    } \
    __syncthreads(); \
    int rg = (t >> 4) * 4, cg = (t & 15) * 4; \
    float acc[8][8]; \
    _Pragma("unroll") \
    for (int i = 0; i < 8; i++) \
        _Pragma("unroll") \
        for (int j = 0; j < 8; j++) acc[i][j] = 0.f; \
    _Pragma("unroll 2") \
    for (int f = 0; f < 32; f++) { \
        float4 qa = *(const float4*)&qsT[f * 132 + rg]; \
        float4 qb = *(const float4*)&qsT[f * 132 + 64 + rg]; \
        float4 ca = *(const float4*)&csT[f * 132 + cg]; \
        float4 cb = *(const float4*)&csT[f * 132 + 64 + cg]; \
        float qv[8] = {qa.x, qa.y, qa.z, qa.w, qb.x, qb.y, qb.z, qb.w}; \
        float cv[8] = {ca.x, ca.y, ca.z, ca.w, cb.x, cb.y, cb.z, cb.w}; \
        _Pragma("unroll") \
        for (int i = 0; i < 8; i++) \
            _Pragma("unroll") \
            for (int j = 0; j < 8; j++) acc[i][j] += qv[i] * cv[j]; \
    }

__global__ __launch_bounds__(256, 4) void pairdot_minmax(
        const float* __restrict__ Q, const float* __restrict__ C,
        float* __restrict__ bmin, float* __restrict__ bmax) {
    PD_STAGE_AND_DOT
    float lmin = acc[0][0], lmax = acc[0][0];
#pragma unroll
    for (int i = 0; i < 8; i++)
#pragma unroll
        for (int j = 0; j < 8; j++) {
            lmin = fminf(lmin, acc[i][j]);
            lmax = fmaxf(lmax, acc[i][j]);
        }
    __shared__ float rmin[256], rmax[256];
    rmin[t] = lmin; rmax[t] = lmax;
    __syncthreads();
    for (int s = 128; s > 0; s >>= 1) {
        if (t < s) { rmin[t] = fminf(rmin[t], rmin[t + s]); rmax[t] = fmaxf(rmax[t], rmax[t + s]); }
        __syncthreads();
    }
    if (t == 0) { bmin[blk] = rmin[0]; bmax[blk] = rmax[0]; }
}

// ---------------- global min/max reduce (1 block) + zero counts ----------------
__global__ void minmax_kernel(const float* __restrict__ bmin, const float* __restrict__ bmax,
                              float* __restrict__ lohi, float* __restrict__ counts) {
    __shared__ float rmin[256], rmax[256];
    int t = threadIdx.x;
    float lmin = 1e30f, lmax = -1e30f;
    for (int i = t; i < 512; i += 256) { lmin = fminf(lmin, bmin[i]); lmax = fmaxf(lmax, bmax[i]); }
    rmin[t] = lmin; rmax[t] = lmax;
    __syncthreads();
    for (int s = 128; s > 0; s >>= 1) {
        if (t < s) { rmin[t] = fminf(rmin[t], rmin[t + s]); rmax[t] = fmaxf(rmax[t], rmax[t + s]); }
        __syncthreads();
    }
    if (t == 0) { lohi[0] = rmin[0]; lohi[1] = rmax[0]; }
    if (t < BINS) counts[t] = 0.f;
}

// ---------------- pass 2: recompute dots, bit-sliced ballot histogram ----------------
__global__ __launch_bounds__(256, 4) void pairdot_hist(
        const float* __restrict__ Q, const float* __restrict__ C,
        const float* __restrict__ lohi, float* __restrict__ counts) {
    PD_STAGE_AND_DOT
    float lo = lohi[0], hi = lohi[1];
    float scale = (float)BINS / (hi - lo);
    int lane = t & 63;
    int cnt = 0;   // lane L accumulates count for bin (L & 15)
#pragma unroll
    for (int i = 0; i < 8; i++)
#pragma unroll
        for (int j = 0; j < 8; j++) {
            int idx = (int)floorf((acc[i][j] - lo) * scale);
            idx = min(max(idx, 0), BINS - 1);
            unsigned long long b0 = __ballot((idx & 1) != 0);
            unsigned long long b1 = __ballot((idx & 2) != 0);
            unsigned long long b2 = __ballot((idx & 4) != 0);
            unsigned long long b3 = __ballot((idx & 8) != 0);
            unsigned long long msk = ((lane & 1) ? b0 : ~b0);
            msk &= ((lane & 2) ? b1 : ~b1);
            msk &= ((lane & 4) ? b2 : ~b2);
            msk &= ((lane & 8) ? b3 : ~b3);
            cnt += __popcll(msk);
        }
    __shared__ float wbins[4][BINS];
    int wave = t >> 6;
    if (lane < BINS) wbins[wave][lane] = (float)cnt;
    __syncthreads();
    if (t < BINS) {
        atomicAdd(&counts[t], wbins[0][t] + wbins[1][t] + wbins[2][t] + wbins[3][t]);
    }
}

// ---------------- NTN + histogram concat + fc1 + fc2 head ----------------
__global__ void final_kernel(const float* __restrict__ e1, const float* __restrict__ e2,
                             const float* __restrict__ ntnW, const float* __restrict__ ntnV,
                             const float* __restrict__ ntnb, const float* __restrict__ counts,
                             const float* __restrict__ fc1W, const float* __restrict__ fc1b,
                             const float* __restrict__ fc2W, const float* __restrict__ fc2b,
                             float* __restrict__ out) {
    int b = blockIdx.x;
    int t = threadIdx.x;
    __shared__ float a1[32], a2[32], red[256], z[32], u[16];
    if (t < 32) a1[t] = e1[b * 32 + t];
    else if (t < 64) a2[t - 32] = e2[b * 32 + t - 32];
    __syncthreads();
    int tt = t >> 4, g = t & 15;
    float p = 0.f;
#pragma unroll
    for (int ii = 0; ii < 2; ii++) {
        int i = g + 16 * ii;
        float d = 0.f;
        const float* wr = ntnW + (tt * 32 + i) * 32;
        for (int j = 0; j < 32; j++) d += wr[j] * a2[j];
        p += a1[i] * d;
    }
    red[t] = p;
    __syncthreads();
    if (t < 16) {
        float s = 0.f;
        for (int g2 = 0; g2 < 16; g2++) s += red[t * 16 + g2];
        float lin = ntnb[t];
        for (int i = 0; i < 32; i++) lin += ntnV[t * 64 + i] * a1[i];
        for (int i = 0; i < 32; i++) lin += ntnV[t * 64 + 32 + i] * a2[i];
        z[t] = fmaxf(s + lin, 0.f);
    } else if (t < 32) {
        float tot = 0.f;
        for (int i = 0; i < BINS; i++) tot += counts[i];
        z[t] = counts[t - 16] / tot;
    }
    __syncthreads();
    if (t < 16) {
        float a = fc1b[t];
        for (int i = 0; i < 32; i++) a += fc1W[t * 32 + i] * z[i];
        u[t] = fmaxf(a, 0.f);
    }
    __syncthreads();
    if (t == 0) {
        float a = fc2b[0];
        for (int i = 0; i < 16; i++) a += fc2W[i] * u[i];
        out[b] = 1.f / (1.f + expf(-a));
    }
}

extern "C" void kernel_launch(void* const* d_in, const int* in_sizes, int n_in,
                              void* d_out, int out_size, void* d_ws, size_t ws_size,
                              hipStream_t stream) {
    const float* xq   = (const float*)d_in[0];
    const float* xc   = (const float*)d_in[1];
    const int*   eq   = (const int*)d_in[2];
    const int*   ec   = (const int*)d_in[3];
    const float* W1   = (const float*)d_in[4];
    const float* b1   = (const float*)d_in[5];
    const float* W2   = (const float*)d_in[6];
    const float* b2   = (const float*)d_in[7];
    const float* W3   = (const float*)d_in[8];
    const float* b3   = (const float*)d_in[9];
    const float* Watt = (const float*)d_in[10];
    const float* ntnW = (const float*)d_in[11];
    const float* ntnV = (const float*)d_in[12];
    const float* ntnb = (const float*)d_in[13];
    const float* fc1W = (const float*)d_in[14];
    const float* fc1b = (const float*)d_in[15];
    const float* fc2W = (const float*)d_in[16];
    const float* fc2b = (const float*)d_in[17];
    float* out = (float*)d_out;
    float* ws  = (float*)d_ws;

    // ---- workspace layout (float indices), [2B] contiguous buffers ----
    float* O3   = ws;                            // 2*B*N*32  = 2097152
    float* e12  = O3 + 2097152;                  // 8192
    float* bmin = e12 + 8192;                    // 2048 (512 used)
    float* bmax = bmin + 2048;                   // 2048 (512 used)
    float* lohi = bmax + 2048;                   // 2
    float* cntw = lohi + 2;                      // 16
    int*   off  = (int*)(ws + 2109504);          // 2B*257 = 65792 ints
    u16*   srcs = (u16*)(off + 65792);           // 2B*E u16 = 262144 floats
    float* dvsg = ws + 2437440;                  // 2B*256 = 65536
    float* O1   = ws + 3223872;                  // 2*B*N*128 = 8388608
    float* O2   = O1 + 8388608;                  // 2*B*N*64  = 4194304

    float* O3Q = O3;
    float* O3C = O3 + (size_t)BB * NN * 32;
    float* e1w = e12;
    float* e2w = e12 + BB * 32;

    csr_kernel<<<2 * BB, 256, 0, stream>>>(eq, ec, off, srcs, dvsg);

    gcn_fused4<128, 128, true, 1><<<4 * 2 * BB, 512, 0, stream>>>(
        xq, xc, W1, b1, off, srcs, dvsg, O1);
    gcn_fused4<128, 64, true, 1><<<2 * 2 * BB, 512, 0, stream>>>(
        O1, O1 + (size_t)BB * NN * 128, W2, b2, off, srcs, dvsg, O2);
    gcn_fused4<64, 32, false, 2><<<2 * 2 * BB, 512, 0, stream>>>(
        O2, O2 + (size_t)BB * NN * 64, W3, b3, off, srcs, dvsg, O3);

    attpool_kernel<<<2 * BB, 256, 0, stream>>>(O3, Watt, e12);

    pairdot_minmax<<<BB * 4, 256, 0, stream>>>(O3Q, O3C, bmin, bmax);
    minmax_kernel<<<1, 256, 0, stream>>>(bmin, bmax, lohi, cntw);
    pairdot_hist<<<BB * 4, 256, 0, stream>>>(O3Q, O3C, lohi, cntw);

    final_kernel<<<BB, 256, 0, stream>>>(e1w, e2w, ntnW, ntnV, ntnb, cntw,
                                         fc1W, fc1b, fc2W, fc2b, out);
}